// Round 14
// baseline (545.911 us; speedup 1.0000x reference)
//
#include <hip/hip_runtime.h>
#include <hip/hip_bf16.h>
#include <math.h>

typedef __hip_bfloat16 bf16;
typedef __attribute__((ext_vector_type(8))) short bf16x8;
typedef __attribute__((ext_vector_type(4))) float f32x4;

static constexpr int B_  = 4;
static constexpr int Hh  = 112, Ww = 112;
static constexpr int Nn  = Hh * Ww;        // 12544
static constexpr int Cc  = 256;
static constexpr int M_  = B_ * Nn;        // 50176
static constexpr int GH_ = 4;
static constexpr int HID_ = 1024;
static constexpr int TG_ = 256;            // 16*16 windows
static constexpr int T__ = 49;             // 7*7 tokens per window
static constexpr float SCALE_ = 0.17677669529663687f;  // 32^-0.5

__device__ __forceinline__ float toF(const bf16 v)  { return __bfloat162float(v); }
__device__ __forceinline__ float toF(const float v) { return v; }
__device__ __forceinline__ void st_out(float* p, float v) { *p = v; }
__device__ __forceinline__ void st_out(bf16* p, float v)  { *p = __float2bfloat16(v); }

// branch-free erf, Abramowitz-Stegun 7.1.26 (|err| <= 1.5e-7, far below bf16 ulp).
__device__ __forceinline__ float erf_fast(float x) {
  float ax = __builtin_fabsf(x);
  float t  = __builtin_amdgcn_rcpf(fmaf(0.3275911f, ax, 1.0f));
  float p  = fmaf(t, 1.061405429f, -1.453152027f);
  p = fmaf(t, p, 1.421413741f);
  p = fmaf(t, p, -0.284496736f);
  p = fmaf(t, p, 0.254829592f);
  p = p * t;
  float r = fmaf(-p, __expf(-ax * ax), 1.0f);
  return copysignf(r, x);
}

// async global->LDS 16B copy (direct-to-LDS, no VGPR roundtrip). LDS dest is
// wave-uniform base + lane*16 — caller must arrange lane-ordered contiguity.
__device__ __forceinline__ void gload_lds16(const bf16* g, bf16* l) {
  using gvoid = const __attribute__((address_space(1))) void;
  using lvoid = __attribute__((address_space(3))) void;
  __builtin_amdgcn_global_load_lds((gvoid*)g, (lvoid*)l, 16, 0, 0);
}

__global__ void guard_fill_kernel(float* out) {
  out[threadIdx.x + blockIdx.x * 256] = 1.0e6f;  // sentinel: workspace guard tripped
}

// ---------------- fused weight convert+transpose (R13 graph-merge layout) ----------------
// QW  = [Gq_t ; Lq_t]              (256 x 256)   rows 0-127 Gq, 128-255 Lq
// Gkv_t (256 x 256), Lkv_t (256 x 256)
// PJ  = blockdiag(Gp, Lp) as Wt    (256 x 256)   row n<128: [Gp_t[n] | 0], n>=128: [0 | Lp_t[n-128]]
// f1_t (1024 x 256), f2_t (256 x 1024)
__global__ __launch_bounds__(256) void convert_all_kernel(
    const float* __restrict__ gq, const float* __restrict__ lq,
    const float* __restrict__ gkv, const float* __restrict__ lkv,
    const float* __restrict__ gp, const float* __restrict__ lp,
    const float* __restrict__ f1, const float* __restrict__ f2,
    bf16* __restrict__ wt) {
  int idx = blockIdx.x * 256 + threadIdx.x;   // grid sized exactly: 786432 = 3072*256
  float v;
  if (idx < 32768) {                       // Gq: N=128 K=256
    int n = idx / 256, k = idx - n * 256;
    v = gq[(size_t)k * 128 + n];
  } else if (idx < 65536) {                // Lq: N=128 K=256
    int loc = idx - 32768;
    int n = loc / 256, k = loc - n * 256;
    v = lq[(size_t)k * 128 + n];
  } else if (idx < 131072) {               // Gkv: N=256 K=256
    int loc = idx - 65536;
    int n = loc / 256, k = loc - n * 256;
    v = gkv[(size_t)k * 256 + n];
  } else if (idx < 196608) {               // Lkv: N=256 K=256
    int loc = idx - 131072;
    int n = loc / 256, k = loc - n * 256;
    v = lkv[(size_t)k * 256 + n];
  } else if (idx < 262144) {               // PJ blockdiag: N=256 K=256
    int loc = idx - 196608;
    int n = loc >> 8, k = loc & 255;
    if (n < 128 && k < 128)       v = gp[(size_t)k * 128 + n];
    else if (n >= 128 && k >= 128) v = lp[(size_t)(k - 128) * 128 + (n - 128)];
    else                           v = 0.f;
  } else if (idx < 524288) {               // f1: N=1024 K=256
    int loc = idx - 262144;
    int n = loc / 256, k = loc - n * 256;
    v = f1[(size_t)k * 1024 + n];
  } else {                                 // f2: N=256 K=1024
    int loc = idx - 524288;
    int n = loc / 1024, k = loc - n * 1024;
    v = f2[(size_t)k * 256 + n];
  }
  wt[idx] = __float2bfloat16(v);
}

// ---------------- dual LayerNorm: wave per row (fastest measured form, 40.2us; structural) ----------------
__global__ __launch_bounds__(256) void ln_dual_kernel(const float* __restrict__ x,
                                                      const float* __restrict__ xr,
                                                      const float* __restrict__ g,
                                                      const float* __restrict__ bta,
                                                      bf16* __restrict__ xn,
                                                      bf16* __restrict__ xrn) {
  const int tid = threadIdx.x;
  const int row = blockIdx.x * 4 + (tid >> 6);
  const int lane = tid & 63;
  const int c0 = lane * 4;
  const float* src = blockIdx.y ? xr : x;
  bf16* dst = blockIdx.y ? xrn : xn;
  float4 v = *(const float4*)(src + (size_t)row * Cc + c0);
  float s  = v.x + v.y + v.z + v.w;
  float ss = v.x * v.x + v.y * v.y + v.z * v.z + v.w * v.w;
  #pragma unroll
  for (int off = 1; off < 64; off <<= 1) {
    s  += __shfl_xor(s, off);
    ss += __shfl_xor(ss, off);
  }
  float mean = s * (1.0f / Cc);
  float var  = ss * (1.0f / Cc) - mean * mean;
  float r = rsqrtf(var + 1e-5f);
  float4 gv = *(const float4*)(g + c0);
  float4 bv = *(const float4*)(bta + c0);
  bf16 o[4];
  o[0] = __float2bfloat16((v.x - mean) * r * gv.x + bv.x);
  o[1] = __float2bfloat16((v.y - mean) * r * gv.y + bv.y);
  o[2] = __float2bfloat16((v.z - mean) * r * gv.z + bv.z);
  o[3] = __float2bfloat16((v.w - mean) * r * gv.w + bv.w);
  *(uint2*)(dst + (size_t)row * Cc + c0) = *(uint2*)o;
}

// ---------------- 7x7 average pool: 64 threads, 4 channels/lane ----------------
__global__ __launch_bounds__(64) void pool_kernel(const bf16* __restrict__ xrn,
                                                  bf16* __restrict__ pooled) {
  const int lane = threadIdx.x;
  const int c0 = lane * 4;
  const int g  = blockIdx.x;   // gh*16+gw
  const int b  = blockIdx.y;
  const int gh = g >> 4, gw = g & 15;
  float acc[4] = {};
  union U4 { uint2 u; bf16 e[4]; };
  #pragma unroll
  for (int i = 0; i < 7; i++)
    for (int j = 0; j < 7; j++) {
      int n = (gh * 7 + i) * Ww + gw * 7 + j;
      U4 r4;
      r4.u = *(const uint2*)(xrn + ((size_t)b * Nn + n) * Cc + c0);
      #pragma unroll
      for (int u = 0; u < 4; u++) acc[u] += toF(r4.e[u]);
    }
  bf16 o[4];
  #pragma unroll
  for (int u = 0; u < 4; u++) o[u] = __float2bfloat16(acc[u] * (1.0f / 49.0f));
  *(uint2*)(pooled + ((size_t)b * TG_ + g) * Cc + c0) = *(uint2*)o;
}

// ---------------- MFMA GEMM with direct global->LDS staging (m97 recipe) ----------------
// out[M,N] = A[M,K](bf16) @ Wt[N,K](bf16,transposed) + bias; M%128==0, N%128==0, K%BK==0.
// bias2 (optional): col<128 -> bias[col], col>=128 -> bias2[col-128] (merged dual-head GEMMs).
// BK=64 for fc1 (R12: doubles MFMA-per-barrier at shallow K; fc1 left top-5).
template <typename OutT, bool RES, int BK = 32>
__global__ __launch_bounds__(256) void mfma_gemm_kernel(const bf16* __restrict__ A,
                                                        const bf16* __restrict__ Wt,
                                                        const float* __restrict__ bias,
                                                        const float* __restrict__ bias2,
                                                        const float* __restrict__ res,
                                                        OutT* __restrict__ out,
                                                        int M, int N, int K) {
  __shared__ __align__(16) bf16 As[128 * BK];
  __shared__ __align__(16) bf16 Bs[128 * BK];
  constexpr int LPR = BK / 8;     // lanes per row (16B chunks of BK*2 bytes)
  constexpr int RPI = 512 / BK;   // rows per staging instr per wave
  constexpr int NI  = BK / 16;    // staging instrs per wave per matrix
  const int tid = threadIdx.x;
  const int bm = blockIdx.y * 128, bn = blockIdx.x * 128;
  const int lane = tid & 63, w = tid >> 6;
  const int wm = (w >> 1) * 64, wn = (w & 1) * 64;

  const int rbase = w * 32 + (lane / LPR);
  const int kq    = (lane % LPR) * 8;
  const bf16* Ag[NI];
  const bf16* Bg[NI];
  bf16* Al[NI];
  bf16* Bl[NI];
  #pragma unroll
  for (int t = 0; t < NI; t++) {
    const int srow = rbase + t * RPI;
    Ag[t] = A  + (size_t)(bm + srow) * K + kq;
    Al[t] = &As[srow * BK + kq];
    Bg[t] = Wt + (size_t)(bn + srow) * K + kq;
    Bl[t] = &Bs[srow * BK + kq];
  }

  f32x4 acc[4][4];
  #pragma unroll
  for (int i = 0; i < 4; i++)
    #pragma unroll
    for (int j = 0; j < 4; j++) acc[i][j] = (f32x4){0.f, 0.f, 0.f, 0.f};

  const int r16  = lane & 15;
  const int koct = (lane >> 4) * 8;
  const int mrow = wm + r16;
  const int nrow = wn + r16;

  for (int k0 = 0; k0 < K; k0 += BK) {
    #pragma unroll
    for (int t = 0; t < NI; t++) {
      gload_lds16(Ag[t] + k0, Al[t]);
      gload_lds16(Bg[t] + k0, Bl[t]);
    }
    __syncthreads();   // drains vmcnt (global_load_lds) before any frag read
    #pragma unroll
    for (int kk = 0; kk < BK / 32; kk++) {
      bf16x8 af[4], bfr[4];
      #pragma unroll
      for (int i = 0; i < 4; i++) af[i]  = *(const bf16x8*)&As[(mrow + i * 16) * BK + kk * 32 + koct];
      #pragma unroll
      for (int j = 0; j < 4; j++) bfr[j] = *(const bf16x8*)&Bs[(nrow + j * 16) * BK + kk * 32 + koct];
      #pragma unroll
      for (int i = 0; i < 4; i++)
        #pragma unroll
        for (int j = 0; j < 4; j++)
          acc[i][j] = __builtin_amdgcn_mfma_f32_16x16x32_bf16(af[i], bfr[j], acc[i][j], 0, 0, 0);
    }
    __syncthreads();
  }

  const int r0 = (lane >> 4) * 4;
  #pragma unroll
  for (int j = 0; j < 4; j++) {
    const int col = bn + wn + j * 16 + r16;
    const float bv = (bias2 && col >= 128) ? bias2[col - 128] : bias[col];
    #pragma unroll
    for (int i = 0; i < 4; i++) {
      const int rowb = bm + wm + i * 16 + r0;
      #pragma unroll
      for (int r = 0; r < 4; r++) {
        size_t ro = (size_t)(rowb + r) * N + col;
        float v = acc[i][j][r] + bv;
        if (RES) v += res[ro];
        st_out(out + ro, v);
      }
    }
  }
}

// ---------------- MFMA flash global attention ----------------
// q read from q_cat cols 0-127 (row stride 256); out to attn_cat cols 0-127.
__global__ __launch_bounds__(256) void gattn_kernel(const bf16* __restrict__ q,
                                                    const bf16* __restrict__ kv,
                                                    bf16* __restrict__ out) {
  __shared__ __align__(16) bf16 Ks[256][40];
  __shared__ __align__(16) bf16 Vt[32][264];
  __shared__ __align__(16) bf16 Ps[4][32][40];
  const int tid = threadIdx.x;
  const int lane = tid & 63, w = tid >> 6;
  const int h = blockIdx.y, b = blockIdx.z;
  const int n0 = blockIdx.x * 128;
  const int r16 = lane & 15, oct = (lane >> 4) * 8;
  const bf16* kvb = kv + (size_t)b * TG_ * 256;

  {
    const int key = tid;
    const bf16* kp = kvb + (size_t)key * 256 + h * 32;
    *(uint4*)&Ks[key][0]  = *(const uint4*)(kp);
    *(uint4*)&Ks[key][8]  = *(const uint4*)(kp + 8);
    *(uint4*)&Ks[key][16] = *(const uint4*)(kp + 16);
    *(uint4*)&Ks[key][24] = *(const uint4*)(kp + 24);
    union { uint4 u[4]; bf16 e[32]; } vv;
    vv.u[0] = *(const uint4*)(kp + 128);
    vv.u[1] = *(const uint4*)(kp + 136);
    vv.u[2] = *(const uint4*)(kp + 144);
    vv.u[3] = *(const uint4*)(kp + 152);
    #pragma unroll
    for (int d = 0; d < 32; d++) Vt[d][key] = vv.e[d];
  }
  const size_t qbase0 = ((size_t)(b * Nn + n0 + w * 32 + r16)) * 256 + h * 32 + oct;
  bf16x8 aq0 = *(const bf16x8*)(q + qbase0);
  bf16x8 aq1 = *(const bf16x8*)(q + qbase0 + (size_t)16 * 256);
  __syncthreads();

  f32x4 rs0 = {0.f, 0.f, 0.f, 0.f}, rs1 = {0.f, 0.f, 0.f, 0.f};
  f32x4 ov[2][2];
  #pragma unroll
  for (int i = 0; i < 2; i++)
    #pragma unroll
    for (int dt = 0; dt < 2; dt++) ov[i][dt] = (f32x4){0.f, 0.f, 0.f, 0.f};

  for (int c0 = 0; c0 < 256; c0 += 32) {
    #pragma unroll
    for (int t = 0; t < 2; t++) {
      bf16x8 bk = *(const bf16x8*)&Ks[c0 + t * 16 + r16][oct];
      f32x4 s0 = __builtin_amdgcn_mfma_f32_16x16x32_bf16(aq0, bk, (f32x4){0.f,0.f,0.f,0.f}, 0, 0, 0);
      f32x4 s1 = __builtin_amdgcn_mfma_f32_16x16x32_bf16(aq1, bk, (f32x4){0.f,0.f,0.f,0.f}, 0, 0, 0);
      const int prow = (lane >> 4) * 4;
      const int pcol = t * 16 + r16;
      #pragma unroll
      for (int r = 0; r < 4; r++) {
        bf16 pb0 = __float2bfloat16(__expf(s0[r] * SCALE_));
        bf16 pb1 = __float2bfloat16(__expf(s1[r] * SCALE_));
        rs0[r] += toF(pb0);
        rs1[r] += toF(pb1);
        Ps[w][prow + r][pcol]      = pb0;
        Ps[w][16 + prow + r][pcol] = pb1;
      }
    }
    bf16x8 ap0 = *(const bf16x8*)&Ps[w][r16][oct];
    bf16x8 ap1 = *(const bf16x8*)&Ps[w][16 + r16][oct];
    #pragma unroll
    for (int dt = 0; dt < 2; dt++) {
      bf16x8 bv = *(const bf16x8*)&Vt[dt * 16 + r16][c0 + oct];
      ov[0][dt] = __builtin_amdgcn_mfma_f32_16x16x32_bf16(ap0, bv, ov[0][dt], 0, 0, 0);
      ov[1][dt] = __builtin_amdgcn_mfma_f32_16x16x32_bf16(ap1, bv, ov[1][dt], 0, 0, 0);
    }
  }
  #pragma unroll
  for (int off = 1; off < 16; off <<= 1) {
    #pragma unroll
    for (int r = 0; r < 4; r++) {
      rs0[r] += __shfl_xor(rs0[r], off);
      rs1[r] += __shfl_xor(rs1[r], off);
    }
  }
  const int orow0 = b * Nn + n0 + w * 32 + (lane >> 4) * 4;
  #pragma unroll
  for (int r = 0; r < 4; r++) {
    float inv0 = 1.0f / rs0[r];
    float inv1 = 1.0f / rs1[r];
    size_t ro0 = (size_t)(orow0 + r) * 256 + h * 32;
    size_t ro1 = ro0 + (size_t)16 * 256;
    #pragma unroll
    for (int dt = 0; dt < 2; dt++) {
      out[ro0 + dt * 16 + r16] = __float2bfloat16(ov[0][dt][r] * inv0);
      out[ro1 + dt * 16 + r16] = __float2bfloat16(ov[1][dt][r] * inv1);
    }
  }
}

// ---------------- local window attention, MFMA version ----------------
// ql read from q_cat cols 128-255 (flat rows, gather via window map); kvl is FLAT
// (M x 256); output un-windowed on store into attn_cat cols 128-255.
__global__ __launch_bounds__(256) void lattn_kernel(const bf16* __restrict__ ql,
                                                    const bf16* __restrict__ kvl,
                                                    bf16* __restrict__ out) {
  __shared__ __align__(16) bf16 Ks[4][64][40];   // per-head K rows (keys 0..48; 49..63 garbage, masked)
  __shared__ __align__(16) bf16 Vt[4][32][72];   // per-head V^T; keys 49..63 zeroed (NaN-garbage * 0 = NaN!)
  __shared__ __align__(16) bf16 Ps[4][64][72];   // per-head P rows (A-operand for PV)
  const int tid = threadIdx.x;
  const int lane = tid & 63, w = tid >> 6;       // w = head
  const int g = blockIdx.x, b = blockIdx.y;
  const int gh = g >> 4, gw = g & 15;
  const int r16 = lane & 15, oct = (lane >> 4) * 8;
  const int nw0 = (gh * 7) * Ww + gw * 7;        // flat pixel of window token 0

  // cooperative stage: 49 tokens x 256 cols of kvl (flat rows) -> Ks (rows) + Vt (transposed)
  for (int u = tid; u < T__ * 32; u += 256) {
    int m = u >> 5, c8 = u & 31;
    int im = m / 7, jm = m - im * 7;
    int nm = nw0 + im * Ww + jm;
    union { uint4 q4; bf16 e[8]; } ch;
    ch.q4 = *(const uint4*)(kvl + ((size_t)b * Nn + nm) * 256 + c8 * 8);
    if (c8 < 16) {
      int h = c8 >> 2, d0 = (c8 & 3) * 8;
      *(uint4*)&Ks[h][m][d0] = ch.q4;
    } else {
      int cv = c8 - 16;
      int h = cv >> 2, d0 = (cv & 3) * 8;
      #pragma unroll
      for (int e = 0; e < 8; e++) Vt[h][d0 + e][m] = ch.e[e];
    }
  }
  // zero V^T pad keys 49..63 (4 heads x 32 d x 15 keys)
  for (int z = tid; z < 4 * 32 * 15; z += 256) {
    int h = z / 480, rem = z - h * 480;
    int d = rem / 15, key = 49 + (rem - d * 15);
    Vt[h][d][key] = __float2bfloat16(0.f);
  }
  // Q fragments from q_cat cols 128+ (flat rows; L2-resident)
  bf16x8 aq[4];
  #pragma unroll
  for (int i = 0; i < 4; i++) {
    int qr = 16 * i + r16;
    if (qr > 48) qr = 48;                       // clamp pad rows (not stored)
    int iq = qr / 7, jq = qr - iq * 7;
    int nq = nw0 + iq * Ww + jq;
    aq[i] = *(const bf16x8*)(ql + ((size_t)b * Nn + nq) * 256 + 128 + w * 32 + oct);
  }
  __syncthreads();

  // S = Q K^T  (64x64 padded, f32)
  f32x4 s[4][4];
  #pragma unroll
  for (int j = 0; j < 4; j++) {
    bf16x8 bk = *(const bf16x8*)&Ks[w][16 * j + r16][oct];
    #pragma unroll
    for (int i = 0; i < 4; i++)
      s[i][j] = __builtin_amdgcn_mfma_f32_16x16x32_bf16(aq[i], bk, (f32x4){0.f,0.f,0.f,0.f}, 0, 0, 0);
  }

  // softmax over all 64 (=49 valid) keys; C-layout: col=lane&15, row=(lane>>4)*4+r
  const int prow = (lane >> 4) * 4;
  float rs[4][4];
  #pragma unroll
  for (int i = 0; i < 4; i++) {
    #pragma unroll
    for (int r = 0; r < 4; r++) {
      float acc = 0.f;
      #pragma unroll
      for (int j = 0; j < 4; j++) {
        float p = __expf(s[i][j][r] * SCALE_);
        if (j == 3 && r16 != 0) p = 0.f;        // cols 49..63 invalid (col48 = j3,r16==0)
        bf16 pb = __float2bfloat16(p);
        Ps[w][16 * i + prow + r][16 * j + r16] = pb;
        acc += toF(pb);
      }
      #pragma unroll
      for (int off = 1; off < 16; off <<= 1) acc += __shfl_xor(acc, off);
      rs[i][r] = acc;
    }
  }
  // no block barrier needed: each wave reads only its own Ps[w] slice (DS ops in-order per wave)

  // O = P V  (A = P rows from LDS, B = V^T rows)
  f32x4 ov[4][2];
  #pragma unroll
  for (int i = 0; i < 4; i++) {
    ov[i][0] = (f32x4){0.f, 0.f, 0.f, 0.f};
    ov[i][1] = (f32x4){0.f, 0.f, 0.f, 0.f};
  }
  #pragma unroll
  for (int kc = 0; kc < 2; kc++) {
    bf16x8 bv0 = *(const bf16x8*)&Vt[w][r16][kc * 32 + oct];
    bf16x8 bv1 = *(const bf16x8*)&Vt[w][16 + r16][kc * 32 + oct];
    #pragma unroll
    for (int i = 0; i < 4; i++) {
      bf16x8 ap = *(const bf16x8*)&Ps[w][16 * i + r16][kc * 32 + oct];
      ov[i][0] = __builtin_amdgcn_mfma_f32_16x16x32_bf16(ap, bv0, ov[i][0], 0, 0, 0);
      ov[i][1] = __builtin_amdgcn_mfma_f32_16x16x32_bf16(ap, bv1, ov[i][1], 0, 0, 0);
    }
  }

  // store rows q < 49, un-windowed (flat), normalized, into attn_cat cols 128-255
  #pragma unroll
  for (int i = 0; i < 4; i++) {
    #pragma unroll
    for (int r = 0; r < 4; r++) {
      int qr = 16 * i + prow + r;
      if (qr < T__) {
        float inv = 1.0f / rs[i][r];
        int iq = qr / 7, jq = qr - iq * 7;
        int nq = nw0 + iq * Ww + jq;
        size_t o = ((size_t)b * Nn + nq) * 256 + 128 + w * 32;
        out[o + r16]      = __float2bfloat16(ov[i][0][r] * inv);
        out[o + 16 + r16] = __float2bfloat16(ov[i][1][r] * inv);
      }
    }
  }
}

// ---------------- combine + LN2 fused: 2 rows/wave, 8 ch/lane ----------------
// proj is [gout|lo] flat-concatenated (M x 256) — one coalesced read, no window math.
__global__ __launch_bounds__(256) void combine_ln_kernel(const float* __restrict__ x,
                                                         const bf16* __restrict__ proj,
                                                         const float* __restrict__ g2,
                                                         const float* __restrict__ b2,
                                                         float* __restrict__ xres,
                                                         bf16* __restrict__ xn2) {
  const int tid = threadIdx.x;
  const int row = blockIdx.x * 8 + (tid >> 5);
  const int sub = tid & 31;
  const int c0 = sub * 8;
  union U8 { uint4 u; bf16 e[8]; } r8;
  r8.u = *(const uint4*)(proj + (size_t)row * 256 + c0);
  const float* xp = x + (size_t)row * Cc + c0;
  float4 v0 = *(const float4*)(xp);
  float4 v1 = *(const float4*)(xp + 4);
  v0.x += toF(r8.e[0]); v0.y += toF(r8.e[1]); v0.z += toF(r8.e[2]); v0.w += toF(r8.e[3]);
  v1.x += toF(r8.e[4]); v1.y += toF(r8.e[5]); v1.z += toF(r8.e[6]); v1.w += toF(r8.e[7]);
  *(float4*)(xres + (size_t)row * Cc + c0)     = v0;
  *(float4*)(xres + (size_t)row * Cc + c0 + 4) = v1;
  float s  = (v0.x + v0.y) + (v0.z + v0.w) + (v1.x + v1.y) + (v1.z + v1.w);
  float ss = v0.x * v0.x + v0.y * v0.y + v0.z * v0.z + v0.w * v0.w
           + v1.x * v1.x + v1.y * v1.y + v1.z * v1.z + v1.w * v1.w;
  #pragma unroll
  for (int off = 1; off < 32; off <<= 1) {
    s  += __shfl_xor(s, off);
    ss += __shfl_xor(ss, off);
  }
  float mean = s * (1.0f / Cc);
  float var  = ss * (1.0f / Cc) - mean * mean;
  float r = rsqrtf(var + 1e-5f);
  float4 gv0 = *(const float4*)(g2 + c0);
  float4 gv1 = *(const float4*)(g2 + c0 + 4);
  float4 bv0 = *(const float4*)(b2 + c0);
  float4 bv1 = *(const float4*)(b2 + c0 + 4);
  __align__(16) bf16 o[8];
  o[0] = __float2bfloat16((v0.x - mean) * r * gv0.x + bv0.x);
  o[1] = __float2bfloat16((v0.y - mean) * r * gv0.y + bv0.y);
  o[2] = __float2bfloat16((v0.z - mean) * r * gv0.z + bv0.z);
  o[3] = __float2bfloat16((v0.w - mean) * r * gv0.w + bv0.w);
  o[4] = __float2bfloat16((v1.x - mean) * r * gv1.x + bv1.x);
  o[5] = __float2bfloat16((v1.y - mean) * r * gv1.y + bv1.y);
  o[6] = __float2bfloat16((v1.z - mean) * r * gv1.z + bv1.z);
  o[7] = __float2bfloat16((v1.w - mean) * r * gv1.w + bv1.w);
  *(uint4*)(xn2 + (size_t)row * Cc + c0) = *(uint4*)o;
}

// ---------------- depthwise 3x3 conv + bias + GELU: 4-row sliding-window walker ----------------
// R14: FOUR output rows per block (R6's density mechanism, second step). Loads 6 input
// rows/col for 4 outputs (1.5 loads/output vs 2), VALU per column-stall 2x again
// (144 FMA + 4 GELU). Live state ~115 floats -> launch_bounds (256,3) (~170 VGPR cap).
// Pre-commit: VGPR>170 or dur regress vs 40us -> revert to 2-row.
static constexpr int TW_ = 14;
__global__ __launch_bounds__(256, 3) void dwconv_gelu_kernel(const bf16* __restrict__ h1,
                                                             const float* __restrict__ w,
                                                             const float* __restrict__ bias,
                                                             bf16* __restrict__ h2) {
  const int tid = threadIdx.x;
  const int c0 = tid * 4;
  const int img = blockIdx.z;
  const int y0  = blockIdx.y * 4;
  const int xt  = blockIdx.x * TW_;
  const size_t ibase = (size_t)img * Nn * HID_;

  float wreg[9][4], breg[4];
  #pragma unroll
  for (int u = 0; u < 4; u++) {
    breg[u] = bias[c0 + u];
    #pragma unroll
    for (int t = 0; t < 9; t++) wreg[t][u] = w[(c0 + u) * 9 + t];
  }

  // 6 input rows: y0-1 .. y0+4 (outputs y0..y0+3; Hh%4==0 so all outputs in range)
  const bf16* rowp[6];
  bool rok[6];
  #pragma unroll
  for (int r = 0; r < 6; r++) {
    int yy = y0 - 1 + r;
    rok[r] = (yy >= 0 && yy < Hh);
    rowp[r] = h1 + ibase + (size_t)(rok[r] ? yy : 0) * Ww * HID_ + c0;
  }

  float wa[6][4], wb[6][4], wc[6][4];
  union U4 { ushort2 u2[2]; bf16 e[4]; };
  auto loadcol = [&](int xcol, float v[6][4]) {
    if (xcol < 0 || xcol >= Ww) {
      #pragma unroll
      for (int r = 0; r < 6; r++)
        #pragma unroll
        for (int u = 0; u < 4; u++) v[r][u] = 0.f;
      return;
    }
    #pragma unroll
    for (int r = 0; r < 6; r++) {
      if (rok[r]) {
        U4 raw;
        *(uint2*)&raw = *(const uint2*)(rowp[r] + (size_t)xcol * HID_);
        #pragma unroll
        for (int u = 0; u < 4; u++) v[r][u] = toF(raw.e[u]);
      } else {
        #pragma unroll
        for (int u = 0; u < 4; u++) v[r][u] = 0.f;
      }
    }
  };
  loadcol(xt - 1, wa);
  loadcol(xt, wb);

  for (int xx = 0; xx < TW_; xx++) {
    const int x = xt + xx;
    loadcol(x + 1, wc);
    #pragma unroll
    for (int p = 0; p < 4; p++) {
      bf16 res[4];
      #pragma unroll
      for (int u = 0; u < 4; u++) {
        float a = breg[u];
        a = fmaf(wa[p + 0][u], wreg[0][u], a);
        a = fmaf(wb[p + 0][u], wreg[1][u], a);
        a = fmaf(wc[p + 0][u], wreg[2][u], a);
        a = fmaf(wa[p + 1][u], wreg[3][u], a);
        a = fmaf(wb[p + 1][u], wreg[4][u], a);
        a = fmaf(wc[p + 1][u], wreg[5][u], a);
        a = fmaf(wa[p + 2][u], wreg[6][u], a);
        a = fmaf(wb[p + 2][u], wreg[7][u], a);
        a = fmaf(wc[p + 2][u], wreg[8][u], a);
        float gl = 0.5f * a * (1.0f + erf_fast(a * 0.7071067811865475f));
        res[u] = __float2bfloat16(gl);
      }
      *(uint2*)(h2 + ibase + (size_t)((y0 + p) * Ww + x) * HID_ + c0) = *(uint2*)res;
    }
    #pragma unroll
    for (int r = 0; r < 6; r++)
      #pragma unroll
      for (int u = 0; u < 4; u++) { wa[r][u] = wb[r][u]; wb[r][u] = wc[r][u]; }
  }
}

extern "C" void kernel_launch(void* const* d_in, const int* in_sizes, int n_in,
                              void* d_out, int out_size, void* d_ws, size_t ws_size,
                              hipStream_t stream) {
  const float* x     = (const float*)d_in[0];
  const float* xrev  = (const float*)d_in[1];
  const float* g1    = (const float*)d_in[2];
  const float* b1    = (const float*)d_in[3];
  const float* g2    = (const float*)d_in[4];
  const float* b2    = (const float*)d_in[5];
  const float* Gq_w  = (const float*)d_in[6];
  const float* Gq_b  = (const float*)d_in[7];
  const float* Gkv_w = (const float*)d_in[8];
  const float* Gkv_b = (const float*)d_in[9];
  const float* Gp_w  = (const float*)d_in[10];
  const float* Gp_b  = (const float*)d_in[11];
  const float* Lq_w  = (const float*)d_in[12];
  const float* Lq_b  = (const float*)d_in[13];
  const float* Lkv_w = (const float*)d_in[14];
  const float* Lkv_b = (const float*)d_in[15];
  const float* Lp_w  = (const float*)d_in[16];
  const float* Lp_b  = (const float*)d_in[17];
  const float* fc1_w = (const float*)d_in[18];
  const float* fc1_b = (const float*)d_in[19];
  const float* dw_w  = (const float*)d_in[20];
  const float* dw_b  = (const float*)d_in[21];
  const float* fc2_w = (const float*)d_in[22];
  const float* fc2_b = (const float*)d_in[23];

  // ---- transposed bf16 weight arena (R13 layout) ----
  const size_t E_QW = 256 * 256;     // [Gq ; Lq]
  const size_t E_GKV = 256 * 256;
  const size_t E_LKV = 256 * 256;
  const size_t E_PJ = 256 * 256;     // blockdiag(Gp, Lp)
  const size_t E_F1 = 1024 * 256, E_F2 = 256 * 1024;
  char* ws = (char*)d_ws;
  bf16* QW_t  = (bf16*)ws;
  bf16* Gkv_t = QW_t  + E_QW;
  bf16* Lkv_t = Gkv_t + E_GKV;
  bf16* PJ_t  = Lkv_t + E_LKV;
  bf16* f1_t  = PJ_t  + E_PJ;
  bf16* f2_t  = f1_t  + E_F1;
  const size_t WT_ELEMS = E_QW + E_GKV + E_LKV + E_PJ + E_F1 + E_F2;  // 786432
  const size_t WT_BYTES = WT_ELEMS * 2;

  // ---- activation arena ----
  const size_t SZ_ROW2 = (size_t)M_ * Cc * 2;
  const size_t SZ_POOL = (size_t)B_ * TG_ * Cc * 2;
  const size_t SZ_KVG  = (size_t)B_ * TG_ * 256 * 2;
  const size_t SZ_H    = (size_t)(2 * Nn) * HID_ * 2;
  char* arena = ws + WT_BYTES;
  bf16* S1       = (bf16*)(arena);                    // xn -> kvl_flat -> xn2
  bf16* S2       = (bf16*)(arena + SZ_ROW2);          // xrn
  bf16* q_cat    = (bf16*)(arena + 2 * SZ_ROW2);      // [q | ql_flat], reused for proj
  bf16* attn_cat = (bf16*)(arena + 3 * SZ_ROW2);      // [gattn | lattn_flat]
  bf16* poolb    = (bf16*)(arena + 4 * SZ_ROW2);
  bf16* kvG      = (bf16*)(arena + 4 * SZ_ROW2 + SZ_POOL);
  const size_t ARENA_A = 4 * SZ_ROW2 + SZ_POOL + SZ_KVG;
  bf16* xn2 = S1;
  bf16* h1  = (bf16*)(arena + SZ_ROW2);               // clobbers S2/q_cat (dead post-combine)
  bf16* h2  = (bf16*)(arena + SZ_ROW2 + SZ_H);
  const size_t ARENA_B = SZ_ROW2 + 2 * SZ_H;

  float* out  = (float*)d_out;
  float* xres = (float*)d_out;
  const size_t NEED = WT_BYTES + (ARENA_A > ARENA_B ? ARENA_A : ARENA_B);
  if (ws_size < NEED) {
    guard_fill_kernel<<<16, 256, 0, stream>>>(out);
    return;
  }

  bf16* xn = S1;  bf16* xrn = S2;  bf16* kvl = S1;  bf16* proj = q_cat;

  // 0) all weights -> bf16 transposed/merged, one kernel
  convert_all_kernel<<<3072, 256, 0, stream>>>(Gq_w, Lq_w, Gkv_w, Lkv_w, Gp_w, Lp_w,
                                               fc1_w, fc2_w, (bf16*)ws);
  // 1) LayerNorm both streams (wave-per-row, fastest measured form)
  ln_dual_kernel<<<dim3(M_ / 4, 2), 256, 0, stream>>>(x, xrev, g1, b1, xn, xrn);
  // 2) 7x7 pool of xrn
  pool_kernel<<<dim3(TG_, B_), 64, 0, stream>>>(xrn, poolb);
  // 3) q_cat = xn @ [Gq|Lq] + [Gq_b|Lq_b]   (merged Gq+Lq, flat rows)
  mfma_gemm_kernel<bf16, false><<<dim3(2, M_ / 128), 256, 0, stream>>>(
      xn, QW_t, Gq_b, Lq_b, nullptr, q_cat, M_, 256, 256);
  // 4) kvl_flat = xrn @ Lkv + b  (flat rows; overwrites S1=xn, which is now dead)
  mfma_gemm_kernel<bf16, false><<<dim3(2, M_ / 128), 256, 0, stream>>>(
      xrn, Lkv_t, Lkv_b, nullptr, nullptr, kvl, M_, 256, 256);
  // 5) kvG = pooled @ Gkv + b
  mfma_gemm_kernel<bf16, false><<<dim3(2, 8), 256, 0, stream>>>(
      poolb, Gkv_t, Gkv_b, nullptr, nullptr, kvG, 1024, 256, 256);
  // 6) global attention -> attn_cat cols 0-127
  gattn_kernel<<<dim3(Nn / 128, GH_, B_), 256, 0, stream>>>(q_cat, kvG, attn_cat);
  // 7) local attention -> attn_cat cols 128-255 (un-windowed on store)
  lattn_kernel<<<dim3(TG_, B_), 256, 0, stream>>>(q_cat, kvl, attn_cat);
  // 8) proj = attn_cat @ blockdiag(Gp,Lp) + [Gp_b|Lp_b]  (merged Gp+Lp; into q_cat space)
  mfma_gemm_kernel<bf16, false><<<dim3(2, M_ / 128), 256, 0, stream>>>(
      attn_cat, PJ_t, Gp_b, Lp_b, nullptr, proj, M_, 256, 256);
  // 9) xres(=d_out) = x + proj; xn2 = LN2(xres)
  combine_ln_kernel<<<M_ / 8, 256, 0, stream>>>(x, proj, g2, b2, xres, xn2);
  // 10-12) MLP in two halves (2 images each); fc1 with BK=64; dwconv 4-row
  for (int half = 0; half < 2; half++) {
    const size_t r0 = (size_t)half * 2 * Nn;
    mfma_gemm_kernel<bf16, false, 64><<<dim3(8, (2 * Nn) / 128), 256, 0, stream>>>(
        xn2 + r0 * Cc, f1_t, fc1_b, nullptr, nullptr, h1, 2 * Nn, 1024, 256);
    dwconv_gelu_kernel<<<dim3(Ww / TW_, Hh / 4, 2), 256, 0, stream>>>(h1, dw_w, dw_b, h2);
    mfma_gemm_kernel<float, true><<<dim3(2, (2 * Nn) / 128), 256, 0, stream>>>(
        h2, f2_t, fc2_b, nullptr, xres + r0 * Cc, out + r0 * Cc, 2 * Nn, 256, 1024);
  }
}

// Round 15
// 526.297 us; speedup vs baseline: 1.0373x; 1.0373x over previous
//
#include <hip/hip_runtime.h>
#include <hip/hip_bf16.h>
#include <math.h>

typedef __hip_bfloat16 bf16;
typedef __attribute__((ext_vector_type(8))) short bf16x8;
typedef __attribute__((ext_vector_type(4))) float f32x4;

static constexpr int B_  = 4;
static constexpr int Hh  = 112, Ww = 112;
static constexpr int Nn  = Hh * Ww;        // 12544
static constexpr int Cc  = 256;
static constexpr int M_  = B_ * Nn;        // 50176
static constexpr int GH_ = 4;
static constexpr int HID_ = 1024;
static constexpr int TG_ = 256;            // 16*16 windows
static constexpr int T__ = 49;             // 7*7 tokens per window
static constexpr float SCALE_ = 0.17677669529663687f;  // 32^-0.5

__device__ __forceinline__ float toF(const bf16 v)  { return __bfloat162float(v); }
__device__ __forceinline__ float toF(const float v) { return v; }
__device__ __forceinline__ void st_out(float* p, float v) { *p = v; }
__device__ __forceinline__ void st_out(bf16* p, float v)  { *p = __float2bfloat16(v); }

// branch-free erf, Abramowitz-Stegun 7.1.26 (|err| <= 1.5e-7, far below bf16 ulp).
__device__ __forceinline__ float erf_fast(float x) {
  float ax = __builtin_fabsf(x);
  float t  = __builtin_amdgcn_rcpf(fmaf(0.3275911f, ax, 1.0f));
  float p  = fmaf(t, 1.061405429f, -1.453152027f);
  p = fmaf(t, p, 1.421413741f);
  p = fmaf(t, p, -0.284496736f);
  p = fmaf(t, p, 0.254829592f);
  p = p * t;
  float r = fmaf(-p, __expf(-ax * ax), 1.0f);
  return copysignf(r, x);
}

// async global->LDS 16B copy (direct-to-LDS, no VGPR roundtrip). LDS dest is
// wave-uniform base + lane*16 — caller must arrange lane-ordered contiguity.
__device__ __forceinline__ void gload_lds16(const bf16* g, bf16* l) {
  using gvoid = const __attribute__((address_space(1))) void;
  using lvoid = __attribute__((address_space(3))) void;
  __builtin_amdgcn_global_load_lds((gvoid*)g, (lvoid*)l, 16, 0, 0);
}

__global__ void guard_fill_kernel(float* out) {
  out[threadIdx.x + blockIdx.x * 256] = 1.0e6f;  // sentinel: workspace guard tripped
}

// ---------------- fused weight convert+transpose (graph-merge layout) ----------------
// QW  = [Gq_t ; Lq_t]              (256 x 256)   rows 0-127 Gq, 128-255 Lq
// Gkv_t (256 x 256), Lkv_t (256 x 256)
// PJ  = blockdiag(Gp, Lp) as Wt    (256 x 256)
// f1_t (1024 x 256), f2_t (256 x 1024)
__global__ __launch_bounds__(256) void convert_all_kernel(
    const float* __restrict__ gq, const float* __restrict__ lq,
    const float* __restrict__ gkv, const float* __restrict__ lkv,
    const float* __restrict__ gp, const float* __restrict__ lp,
    const float* __restrict__ f1, const float* __restrict__ f2,
    bf16* __restrict__ wt) {
  int idx = blockIdx.x * 256 + threadIdx.x;   // grid sized exactly: 786432 = 3072*256
  float v;
  if (idx < 32768) {                       // Gq: N=128 K=256
    int n = idx / 256, k = idx - n * 256;
    v = gq[(size_t)k * 128 + n];
  } else if (idx < 65536) {                // Lq: N=128 K=256
    int loc = idx - 32768;
    int n = loc / 256, k = loc - n * 256;
    v = lq[(size_t)k * 128 + n];
  } else if (idx < 131072) {               // Gkv: N=256 K=256
    int loc = idx - 65536;
    int n = loc / 256, k = loc - n * 256;
    v = gkv[(size_t)k * 256 + n];
  } else if (idx < 196608) {               // Lkv: N=256 K=256
    int loc = idx - 131072;
    int n = loc / 256, k = loc - n * 256;
    v = lkv[(size_t)k * 256 + n];
  } else if (idx < 262144) {               // PJ blockdiag: N=256 K=256
    int loc = idx - 196608;
    int n = loc >> 8, k = loc & 255;
    if (n < 128 && k < 128)       v = gp[(size_t)k * 128 + n];
    else if (n >= 128 && k >= 128) v = lp[(size_t)(k - 128) * 128 + (n - 128)];
    else                           v = 0.f;
  } else if (idx < 524288) {               // f1: N=1024 K=256
    int loc = idx - 262144;
    int n = loc / 256, k = loc - n * 256;
    v = f1[(size_t)k * 1024 + n];
  } else {                                 // f2: N=256 K=1024
    int loc = idx - 524288;
    int n = loc / 1024, k = loc - n * 1024;
    v = f2[(size_t)k * 256 + n];
  }
  wt[idx] = __float2bfloat16(v);
}

// ---------------- dual LayerNorm: wave per row (fastest measured form, 40.2us; structural) ----------------
__global__ __launch_bounds__(256) void ln_dual_kernel(const float* __restrict__ x,
                                                      const float* __restrict__ xr,
                                                      const float* __restrict__ g,
                                                      const float* __restrict__ bta,
                                                      bf16* __restrict__ xn,
                                                      bf16* __restrict__ xrn) {
  const int tid = threadIdx.x;
  const int row = blockIdx.x * 4 + (tid >> 6);
  const int lane = tid & 63;
  const int c0 = lane * 4;
  const float* src = blockIdx.y ? xr : x;
  bf16* dst = blockIdx.y ? xrn : xn;
  float4 v = *(const float4*)(src + (size_t)row * Cc + c0);
  float s  = v.x + v.y + v.z + v.w;
  float ss = v.x * v.x + v.y * v.y + v.z * v.z + v.w * v.w;
  #pragma unroll
  for (int off = 1; off < 64; off <<= 1) {
    s  += __shfl_xor(s, off);
    ss += __shfl_xor(ss, off);
  }
  float mean = s * (1.0f / Cc);
  float var  = ss * (1.0f / Cc) - mean * mean;
  float r = rsqrtf(var + 1e-5f);
  float4 gv = *(const float4*)(g + c0);
  float4 bv = *(const float4*)(bta + c0);
  bf16 o[4];
  o[0] = __float2bfloat16((v.x - mean) * r * gv.x + bv.x);
  o[1] = __float2bfloat16((v.y - mean) * r * gv.y + bv.y);
  o[2] = __float2bfloat16((v.z - mean) * r * gv.z + bv.z);
  o[3] = __float2bfloat16((v.w - mean) * r * gv.w + bv.w);
  *(uint2*)(dst + (size_t)row * Cc + c0) = *(uint2*)o;
}

// ---------------- 7x7 average pool: 64 threads, 4 channels/lane ----------------
__global__ __launch_bounds__(64) void pool_kernel(const bf16* __restrict__ xrn,
                                                  bf16* __restrict__ pooled) {
  const int lane = threadIdx.x;
  const int c0 = lane * 4;
  const int g  = blockIdx.x;   // gh*16+gw
  const int b  = blockIdx.y;
  const int gh = g >> 4, gw = g & 15;
  float acc[4] = {};
  union U4 { uint2 u; bf16 e[4]; };
  #pragma unroll
  for (int i = 0; i < 7; i++)
    for (int j = 0; j < 7; j++) {
      int n = (gh * 7 + i) * Ww + gw * 7 + j;
      U4 r4;
      r4.u = *(const uint2*)(xrn + ((size_t)b * Nn + n) * Cc + c0);
      #pragma unroll
      for (int u = 0; u < 4; u++) acc[u] += toF(r4.e[u]);
    }
  bf16 o[4];
  #pragma unroll
  for (int u = 0; u < 4; u++) o[u] = __float2bfloat16(acc[u] * (1.0f / 49.0f));
  *(uint2*)(pooled + ((size_t)b * TG_ + g) * Cc + c0) = *(uint2*)o;
}

// ---------------- MFMA GEMM with direct global->LDS staging (m97 recipe) ----------------
// out[M,N] = A[M,K](bf16) @ Wt[N,K](bf16,transposed) + bias; M%128==0, N%128==0, K%BK==0.
// bias2 (optional): col<128 -> bias[col], col>=128 -> bias2[col-128] (merged dual-head GEMMs).
// R15: BK=64 on ALL GEMMs (proven on fc1 in R12: halves barrier pairs at shallow K,
// acc/VGPR unchanged — the register-safe axis per R11's occupancy lesson).
template <typename OutT, bool RES, int BK = 64>
__global__ __launch_bounds__(256) void mfma_gemm_kernel(const bf16* __restrict__ A,
                                                        const bf16* __restrict__ Wt,
                                                        const float* __restrict__ bias,
                                                        const float* __restrict__ bias2,
                                                        const float* __restrict__ res,
                                                        OutT* __restrict__ out,
                                                        int M, int N, int K) {
  __shared__ __align__(16) bf16 As[128 * BK];
  __shared__ __align__(16) bf16 Bs[128 * BK];
  constexpr int LPR = BK / 8;     // lanes per row (16B chunks of BK*2 bytes)
  constexpr int RPI = 512 / BK;   // rows per staging instr per wave
  constexpr int NI  = BK / 16;    // staging instrs per wave per matrix
  const int tid = threadIdx.x;
  const int bm = blockIdx.y * 128, bn = blockIdx.x * 128;
  const int lane = tid & 63, w = tid >> 6;
  const int wm = (w >> 1) * 64, wn = (w & 1) * 64;

  const int rbase = w * 32 + (lane / LPR);
  const int kq    = (lane % LPR) * 8;
  const bf16* Ag[NI];
  const bf16* Bg[NI];
  bf16* Al[NI];
  bf16* Bl[NI];
  #pragma unroll
  for (int t = 0; t < NI; t++) {
    const int srow = rbase + t * RPI;
    Ag[t] = A  + (size_t)(bm + srow) * K + kq;
    Al[t] = &As[srow * BK + kq];
    Bg[t] = Wt + (size_t)(bn + srow) * K + kq;
    Bl[t] = &Bs[srow * BK + kq];
  }

  f32x4 acc[4][4];
  #pragma unroll
  for (int i = 0; i < 4; i++)
    #pragma unroll
    for (int j = 0; j < 4; j++) acc[i][j] = (f32x4){0.f, 0.f, 0.f, 0.f};

  const int r16  = lane & 15;
  const int koct = (lane >> 4) * 8;
  const int mrow = wm + r16;
  const int nrow = wn + r16;

  for (int k0 = 0; k0 < K; k0 += BK) {
    #pragma unroll
    for (int t = 0; t < NI; t++) {
      gload_lds16(Ag[t] + k0, Al[t]);
      gload_lds16(Bg[t] + k0, Bl[t]);
    }
    __syncthreads();   // drains vmcnt (global_load_lds) before any frag read
    #pragma unroll
    for (int kk = 0; kk < BK / 32; kk++) {
      bf16x8 af[4], bfr[4];
      #pragma unroll
      for (int i = 0; i < 4; i++) af[i]  = *(const bf16x8*)&As[(mrow + i * 16) * BK + kk * 32 + koct];
      #pragma unroll
      for (int j = 0; j < 4; j++) bfr[j] = *(const bf16x8*)&Bs[(nrow + j * 16) * BK + kk * 32 + koct];
      #pragma unroll
      for (int i = 0; i < 4; i++)
        #pragma unroll
        for (int j = 0; j < 4; j++)
          acc[i][j] = __builtin_amdgcn_mfma_f32_16x16x32_bf16(af[i], bfr[j], acc[i][j], 0, 0, 0);
    }
    __syncthreads();
  }

  const int r0 = (lane >> 4) * 4;
  #pragma unroll
  for (int j = 0; j < 4; j++) {
    const int col = bn + wn + j * 16 + r16;
    const float bv = (bias2 && col >= 128) ? bias2[col - 128] : bias[col];
    #pragma unroll
    for (int i = 0; i < 4; i++) {
      const int rowb = bm + wm + i * 16 + r0;
      #pragma unroll
      for (int r = 0; r < 4; r++) {
        size_t ro = (size_t)(rowb + r) * N + col;
        float v = acc[i][j][r] + bv;
        if (RES) v += res[ro];
        st_out(out + ro, v);
      }
    }
  }
}

// ---------------- MFMA flash global attention ----------------
// q read from q_cat cols 0-127 (row stride 256); out to attn_cat cols 0-127.
__global__ __launch_bounds__(256) void gattn_kernel(const bf16* __restrict__ q,
                                                    const bf16* __restrict__ kv,
                                                    bf16* __restrict__ out) {
  __shared__ __align__(16) bf16 Ks[256][40];
  __shared__ __align__(16) bf16 Vt[32][264];
  __shared__ __align__(16) bf16 Ps[4][32][40];
  const int tid = threadIdx.x;
  const int lane = tid & 63, w = tid >> 6;
  const int h = blockIdx.y, b = blockIdx.z;
  const int n0 = blockIdx.x * 128;
  const int r16 = lane & 15, oct = (lane >> 4) * 8;
  const bf16* kvb = kv + (size_t)b * TG_ * 256;

  {
    const int key = tid;
    const bf16* kp = kvb + (size_t)key * 256 + h * 32;
    *(uint4*)&Ks[key][0]  = *(const uint4*)(kp);
    *(uint4*)&Ks[key][8]  = *(const uint4*)(kp + 8);
    *(uint4*)&Ks[key][16] = *(const uint4*)(kp + 16);
    *(uint4*)&Ks[key][24] = *(const uint4*)(kp + 24);
    union { uint4 u[4]; bf16 e[32]; } vv;
    vv.u[0] = *(const uint4*)(kp + 128);
    vv.u[1] = *(const uint4*)(kp + 136);
    vv.u[2] = *(const uint4*)(kp + 144);
    vv.u[3] = *(const uint4*)(kp + 152);
    #pragma unroll
    for (int d = 0; d < 32; d++) Vt[d][key] = vv.e[d];
  }
  const size_t qbase0 = ((size_t)(b * Nn + n0 + w * 32 + r16)) * 256 + h * 32 + oct;
  bf16x8 aq0 = *(const bf16x8*)(q + qbase0);
  bf16x8 aq1 = *(const bf16x8*)(q + qbase0 + (size_t)16 * 256);
  __syncthreads();

  f32x4 rs0 = {0.f, 0.f, 0.f, 0.f}, rs1 = {0.f, 0.f, 0.f, 0.f};
  f32x4 ov[2][2];
  #pragma unroll
  for (int i = 0; i < 2; i++)
    #pragma unroll
    for (int dt = 0; dt < 2; dt++) ov[i][dt] = (f32x4){0.f, 0.f, 0.f, 0.f};

  for (int c0 = 0; c0 < 256; c0 += 32) {
    #pragma unroll
    for (int t = 0; t < 2; t++) {
      bf16x8 bk = *(const bf16x8*)&Ks[c0 + t * 16 + r16][oct];
      f32x4 s0 = __builtin_amdgcn_mfma_f32_16x16x32_bf16(aq0, bk, (f32x4){0.f,0.f,0.f,0.f}, 0, 0, 0);
      f32x4 s1 = __builtin_amdgcn_mfma_f32_16x16x32_bf16(aq1, bk, (f32x4){0.f,0.f,0.f,0.f}, 0, 0, 0);
      const int prow = (lane >> 4) * 4;
      const int pcol = t * 16 + r16;
      #pragma unroll
      for (int r = 0; r < 4; r++) {
        bf16 pb0 = __float2bfloat16(__expf(s0[r] * SCALE_));
        bf16 pb1 = __float2bfloat16(__expf(s1[r] * SCALE_));
        rs0[r] += toF(pb0);
        rs1[r] += toF(pb1);
        Ps[w][prow + r][pcol]      = pb0;
        Ps[w][16 + prow + r][pcol] = pb1;
      }
    }
    bf16x8 ap0 = *(const bf16x8*)&Ps[w][r16][oct];
    bf16x8 ap1 = *(const bf16x8*)&Ps[w][16 + r16][oct];
    #pragma unroll
    for (int dt = 0; dt < 2; dt++) {
      bf16x8 bv = *(const bf16x8*)&Vt[dt * 16 + r16][c0 + oct];
      ov[0][dt] = __builtin_amdgcn_mfma_f32_16x16x32_bf16(ap0, bv, ov[0][dt], 0, 0, 0);
      ov[1][dt] = __builtin_amdgcn_mfma_f32_16x16x32_bf16(ap1, bv, ov[1][dt], 0, 0, 0);
    }
  }
  #pragma unroll
  for (int off = 1; off < 16; off <<= 1) {
    #pragma unroll
    for (int r = 0; r < 4; r++) {
      rs0[r] += __shfl_xor(rs0[r], off);
      rs1[r] += __shfl_xor(rs1[r], off);
    }
  }
  const int orow0 = b * Nn + n0 + w * 32 + (lane >> 4) * 4;
  #pragma unroll
  for (int r = 0; r < 4; r++) {
    float inv0 = 1.0f / rs0[r];
    float inv1 = 1.0f / rs1[r];
    size_t ro0 = (size_t)(orow0 + r) * 256 + h * 32;
    size_t ro1 = ro0 + (size_t)16 * 256;
    #pragma unroll
    for (int dt = 0; dt < 2; dt++) {
      out[ro0 + dt * 16 + r16] = __float2bfloat16(ov[0][dt][r] * inv0);
      out[ro1 + dt * 16 + r16] = __float2bfloat16(ov[1][dt][r] * inv1);
    }
  }
}

// ---------------- local window attention, MFMA version ----------------
// ql read from q_cat cols 128-255 (flat rows, gather via window map); kvl is FLAT
// (M x 256); output un-windowed on store into attn_cat cols 128-255.
__global__ __launch_bounds__(256) void lattn_kernel(const bf16* __restrict__ ql,
                                                    const bf16* __restrict__ kvl,
                                                    bf16* __restrict__ out) {
  __shared__ __align__(16) bf16 Ks[4][64][40];   // per-head K rows (keys 0..48; 49..63 garbage, masked)
  __shared__ __align__(16) bf16 Vt[4][32][72];   // per-head V^T; keys 49..63 zeroed (NaN-garbage * 0 = NaN!)
  __shared__ __align__(16) bf16 Ps[4][64][72];   // per-head P rows (A-operand for PV)
  const int tid = threadIdx.x;
  const int lane = tid & 63, w = tid >> 6;       // w = head
  const int g = blockIdx.x, b = blockIdx.y;
  const int gh = g >> 4, gw = g & 15;
  const int r16 = lane & 15, oct = (lane >> 4) * 8;
  const int nw0 = (gh * 7) * Ww + gw * 7;        // flat pixel of window token 0

  // cooperative stage: 49 tokens x 256 cols of kvl (flat rows) -> Ks (rows) + Vt (transposed)
  for (int u = tid; u < T__ * 32; u += 256) {
    int m = u >> 5, c8 = u & 31;
    int im = m / 7, jm = m - im * 7;
    int nm = nw0 + im * Ww + jm;
    union { uint4 q4; bf16 e[8]; } ch;
    ch.q4 = *(const uint4*)(kvl + ((size_t)b * Nn + nm) * 256 + c8 * 8);
    if (c8 < 16) {
      int h = c8 >> 2, d0 = (c8 & 3) * 8;
      *(uint4*)&Ks[h][m][d0] = ch.q4;
    } else {
      int cv = c8 - 16;
      int h = cv >> 2, d0 = (cv & 3) * 8;
      #pragma unroll
      for (int e = 0; e < 8; e++) Vt[h][d0 + e][m] = ch.e[e];
    }
  }
  // zero V^T pad keys 49..63 (4 heads x 32 d x 15 keys)
  for (int z = tid; z < 4 * 32 * 15; z += 256) {
    int h = z / 480, rem = z - h * 480;
    int d = rem / 15, key = 49 + (rem - d * 15);
    Vt[h][d][key] = __float2bfloat16(0.f);
  }
  // Q fragments from q_cat cols 128+ (flat rows; L2-resident)
  bf16x8 aq[4];
  #pragma unroll
  for (int i = 0; i < 4; i++) {
    int qr = 16 * i + r16;
    if (qr > 48) qr = 48;                       // clamp pad rows (not stored)
    int iq = qr / 7, jq = qr - iq * 7;
    int nq = nw0 + iq * Ww + jq;
    aq[i] = *(const bf16x8*)(ql + ((size_t)b * Nn + nq) * 256 + 128 + w * 32 + oct);
  }
  __syncthreads();

  // S = Q K^T  (64x64 padded, f32)
  f32x4 s[4][4];
  #pragma unroll
  for (int j = 0; j < 4; j++) {
    bf16x8 bk = *(const bf16x8*)&Ks[w][16 * j + r16][oct];
    #pragma unroll
    for (int i = 0; i < 4; i++)
      s[i][j] = __builtin_amdgcn_mfma_f32_16x16x32_bf16(aq[i], bk, (f32x4){0.f,0.f,0.f,0.f}, 0, 0, 0);
  }

  // softmax over all 64 (=49 valid) keys; C-layout: col=lane&15, row=(lane>>4)*4+r
  const int prow = (lane >> 4) * 4;
  float rs[4][4];
  #pragma unroll
  for (int i = 0; i < 4; i++) {
    #pragma unroll
    for (int r = 0; r < 4; r++) {
      float acc = 0.f;
      #pragma unroll
      for (int j = 0; j < 4; j++) {
        float p = __expf(s[i][j][r] * SCALE_);
        if (j == 3 && r16 != 0) p = 0.f;        // cols 49..63 invalid (col48 = j3,r16==0)
        bf16 pb = __float2bfloat16(p);
        Ps[w][16 * i + prow + r][16 * j + r16] = pb;
        acc += toF(pb);
      }
      #pragma unroll
      for (int off = 1; off < 16; off <<= 1) acc += __shfl_xor(acc, off);
      rs[i][r] = acc;
    }
  }
  // no block barrier needed: each wave reads only its own Ps[w] slice (DS ops in-order per wave)

  // O = P V  (A = P rows from LDS, B = V^T rows)
  f32x4 ov[4][2];
  #pragma unroll
  for (int i = 0; i < 4; i++) {
    ov[i][0] = (f32x4){0.f, 0.f, 0.f, 0.f};
    ov[i][1] = (f32x4){0.f, 0.f, 0.f, 0.f};
  }
  #pragma unroll
  for (int kc = 0; kc < 2; kc++) {
    bf16x8 bv0 = *(const bf16x8*)&Vt[w][r16][kc * 32 + oct];
    bf16x8 bv1 = *(const bf16x8*)&Vt[w][16 + r16][kc * 32 + oct];
    #pragma unroll
    for (int i = 0; i < 4; i++) {
      bf16x8 ap = *(const bf16x8*)&Ps[w][16 * i + r16][kc * 32 + oct];
      ov[i][0] = __builtin_amdgcn_mfma_f32_16x16x32_bf16(ap, bv0, ov[i][0], 0, 0, 0);
      ov[i][1] = __builtin_amdgcn_mfma_f32_16x16x32_bf16(ap, bv1, ov[i][1], 0, 0, 0);
    }
  }

  // store rows q < 49, un-windowed (flat), normalized, into attn_cat cols 128-255
  #pragma unroll
  for (int i = 0; i < 4; i++) {
    #pragma unroll
    for (int r = 0; r < 4; r++) {
      int qr = 16 * i + prow + r;
      if (qr < T__) {
        float inv = 1.0f / rs[i][r];
        int iq = qr / 7, jq = qr - iq * 7;
        int nq = nw0 + iq * Ww + jq;
        size_t o = ((size_t)b * Nn + nq) * 256 + 128 + w * 32;
        out[o + r16]      = __float2bfloat16(ov[i][0][r] * inv);
        out[o + 16 + r16] = __float2bfloat16(ov[i][1][r] * inv);
      }
    }
  }
}

// ---------------- combine + LN2 fused: 2 rows/wave, 8 ch/lane ----------------
// proj is [gout|lo] flat-concatenated (M x 256) — one coalesced read, no window math.
__global__ __launch_bounds__(256) void combine_ln_kernel(const float* __restrict__ x,
                                                         const bf16* __restrict__ proj,
                                                         const float* __restrict__ g2,
                                                         const float* __restrict__ b2,
                                                         float* __restrict__ xres,
                                                         bf16* __restrict__ xn2) {
  const int tid = threadIdx.x;
  const int row = blockIdx.x * 8 + (tid >> 5);
  const int sub = tid & 31;
  const int c0 = sub * 8;
  union U8 { uint4 u; bf16 e[8]; } r8;
  r8.u = *(const uint4*)(proj + (size_t)row * 256 + c0);
  const float* xp = x + (size_t)row * Cc + c0;
  float4 v0 = *(const float4*)(xp);
  float4 v1 = *(const float4*)(xp + 4);
  v0.x += toF(r8.e[0]); v0.y += toF(r8.e[1]); v0.z += toF(r8.e[2]); v0.w += toF(r8.e[3]);
  v1.x += toF(r8.e[4]); v1.y += toF(r8.e[5]); v1.z += toF(r8.e[6]); v1.w += toF(r8.e[7]);
  *(float4*)(xres + (size_t)row * Cc + c0)     = v0;
  *(float4*)(xres + (size_t)row * Cc + c0 + 4) = v1;
  float s  = (v0.x + v0.y) + (v0.z + v0.w) + (v1.x + v1.y) + (v1.z + v1.w);
  float ss = v0.x * v0.x + v0.y * v0.y + v0.z * v0.z + v0.w * v0.w
           + v1.x * v1.x + v1.y * v1.y + v1.z * v1.z + v1.w * v1.w;
  #pragma unroll
  for (int off = 1; off < 32; off <<= 1) {
    s  += __shfl_xor(s, off);
    ss += __shfl_xor(ss, off);
  }
  float mean = s * (1.0f / Cc);
  float var  = ss * (1.0f / Cc) - mean * mean;
  float r = rsqrtf(var + 1e-5f);
  float4 gv0 = *(const float4*)(g2 + c0);
  float4 gv1 = *(const float4*)(g2 + c0 + 4);
  float4 bv0 = *(const float4*)(b2 + c0);
  float4 bv1 = *(const float4*)(b2 + c0 + 4);
  __align__(16) bf16 o[8];
  o[0] = __float2bfloat16((v0.x - mean) * r * gv0.x + bv0.x);
  o[1] = __float2bfloat16((v0.y - mean) * r * gv0.y + bv0.y);
  o[2] = __float2bfloat16((v0.z - mean) * r * gv0.z + bv0.z);
  o[3] = __float2bfloat16((v0.w - mean) * r * gv0.w + bv0.w);
  o[4] = __float2bfloat16((v1.x - mean) * r * gv1.x + bv1.x);
  o[5] = __float2bfloat16((v1.y - mean) * r * gv1.y + bv1.y);
  o[6] = __float2bfloat16((v1.z - mean) * r * gv1.z + bv1.z);
  o[7] = __float2bfloat16((v1.w - mean) * r * gv1.w + bv1.w);
  *(uint4*)(xn2 + (size_t)row * Cc + c0) = *(uint4*)o;
}

// ---------------- depthwise 3x3 conv + bias + GELU: 2-row sliding-window walker ----------------
// R6's proven form (40us). R14's 4-row variant regressed (occupancy 26->15%, 448 blocks
// too few) — 2 rows is the density-vs-residency sweet spot.
static constexpr int TW_ = 14;
__global__ __launch_bounds__(256, 4) void dwconv_gelu_kernel(const bf16* __restrict__ h1,
                                                             const float* __restrict__ w,
                                                             const float* __restrict__ bias,
                                                             bf16* __restrict__ h2) {
  const int tid = threadIdx.x;
  const int c0 = tid * 4;
  const int img = blockIdx.z;
  const int y0  = blockIdx.y * 2;
  const int xt  = blockIdx.x * TW_;
  const size_t ibase = (size_t)img * Nn * HID_;

  float wreg[9][4], breg[4];
  #pragma unroll
  for (int u = 0; u < 4; u++) {
    breg[u] = bias[c0 + u];
    #pragma unroll
    for (int t = 0; t < 9; t++) wreg[t][u] = w[(c0 + u) * 9 + t];
  }

  // 4 input rows: y0-1 .. y0+2 (outputs y0, y0+1 always in range; Hh even)
  const bf16* rowp[4];
  bool rok[4];
  #pragma unroll
  for (int r = 0; r < 4; r++) {
    int yy = y0 - 1 + r;
    rok[r] = (yy >= 0 && yy < Hh);
    rowp[r] = h1 + ibase + (size_t)(rok[r] ? yy : 0) * Ww * HID_ + c0;
  }

  float wa[4][4], wb[4][4], wc[4][4];
  union U4 { ushort2 u2[2]; bf16 e[4]; };
  auto loadcol = [&](int xcol, float v[4][4]) {
    if (xcol < 0 || xcol >= Ww) {
      #pragma unroll
      for (int r = 0; r < 4; r++)
        #pragma unroll
        for (int u = 0; u < 4; u++) v[r][u] = 0.f;
      return;
    }
    #pragma unroll
    for (int r = 0; r < 4; r++) {
      if (rok[r]) {
        U4 raw;
        *(uint2*)&raw = *(const uint2*)(rowp[r] + (size_t)xcol * HID_);
        #pragma unroll
        for (int u = 0; u < 4; u++) v[r][u] = toF(raw.e[u]);
      } else {
        #pragma unroll
        for (int u = 0; u < 4; u++) v[r][u] = 0.f;
      }
    }
  };
  loadcol(xt - 1, wa);
  loadcol(xt, wb);

  for (int xx = 0; xx < TW_; xx++) {
    const int x = xt + xx;
    loadcol(x + 1, wc);
    #pragma unroll
    for (int p = 0; p < 2; p++) {
      bf16 res[4];
      #pragma unroll
      for (int u = 0; u < 4; u++) {
        float a = breg[u];
        a = fmaf(wa[p + 0][u], wreg[0][u], a);
        a = fmaf(wb[p + 0][u], wreg[1][u], a);
        a = fmaf(wc[p + 0][u], wreg[2][u], a);
        a = fmaf(wa[p + 1][u], wreg[3][u], a);
        a = fmaf(wb[p + 1][u], wreg[4][u], a);
        a = fmaf(wc[p + 1][u], wreg[5][u], a);
        a = fmaf(wa[p + 2][u], wreg[6][u], a);
        a = fmaf(wb[p + 2][u], wreg[7][u], a);
        a = fmaf(wc[p + 2][u], wreg[8][u], a);
        float gl = 0.5f * a * (1.0f + erf_fast(a * 0.7071067811865475f));
        res[u] = __float2bfloat16(gl);
      }
      *(uint2*)(h2 + ibase + (size_t)((y0 + p) * Ww + x) * HID_ + c0) = *(uint2*)res;
    }
    #pragma unroll
    for (int r = 0; r < 4; r++)
      #pragma unroll
      for (int u = 0; u < 4; u++) { wa[r][u] = wb[r][u]; wb[r][u] = wc[r][u]; }
  }
}

extern "C" void kernel_launch(void* const* d_in, const int* in_sizes, int n_in,
                              void* d_out, int out_size, void* d_ws, size_t ws_size,
                              hipStream_t stream) {
  const float* x     = (const float*)d_in[0];
  const float* xrev  = (const float*)d_in[1];
  const float* g1    = (const float*)d_in[2];
  const float* b1    = (const float*)d_in[3];
  const float* g2    = (const float*)d_in[4];
  const float* b2    = (const float*)d_in[5];
  const float* Gq_w  = (const float*)d_in[6];
  const float* Gq_b  = (const float*)d_in[7];
  const float* Gkv_w = (const float*)d_in[8];
  const float* Gkv_b = (const float*)d_in[9];
  const float* Gp_w  = (const float*)d_in[10];
  const float* Gp_b  = (const float*)d_in[11];
  const float* Lq_w  = (const float*)d_in[12];
  const float* Lq_b  = (const float*)d_in[13];
  const float* Lkv_w = (const float*)d_in[14];
  const float* Lkv_b = (const float*)d_in[15];
  const float* Lp_w  = (const float*)d_in[16];
  const float* Lp_b  = (const float*)d_in[17];
  const float* fc1_w = (const float*)d_in[18];
  const float* fc1_b = (const float*)d_in[19];
  const float* dw_w  = (const float*)d_in[20];
  const float* dw_b  = (const float*)d_in[21];
  const float* fc2_w = (const float*)d_in[22];
  const float* fc2_b = (const float*)d_in[23];

  // ---- transposed bf16 weight arena ----
  const size_t E_QW = 256 * 256;     // [Gq ; Lq]
  const size_t E_GKV = 256 * 256;
  const size_t E_LKV = 256 * 256;
  const size_t E_PJ = 256 * 256;     // blockdiag(Gp, Lp)
  const size_t E_F1 = 1024 * 256, E_F2 = 256 * 1024;
  char* ws = (char*)d_ws;
  bf16* QW_t  = (bf16*)ws;
  bf16* Gkv_t = QW_t  + E_QW;
  bf16* Lkv_t = Gkv_t + E_GKV;
  bf16* PJ_t  = Lkv_t + E_LKV;
  bf16* f1_t  = PJ_t  + E_PJ;
  bf16* f2_t  = f1_t  + E_F1;
  const size_t WT_ELEMS = E_QW + E_GKV + E_LKV + E_PJ + E_F1 + E_F2;  // 786432
  const size_t WT_BYTES = WT_ELEMS * 2;

  // ---- activation arena ----
  const size_t SZ_ROW2 = (size_t)M_ * Cc * 2;
  const size_t SZ_POOL = (size_t)B_ * TG_ * Cc * 2;
  const size_t SZ_KVG  = (size_t)B_ * TG_ * 256 * 2;
  const size_t SZ_H    = (size_t)(2 * Nn) * HID_ * 2;
  char* arena = ws + WT_BYTES;
  bf16* S1       = (bf16*)(arena);                    // xn -> kvl_flat -> xn2
  bf16* S2       = (bf16*)(arena + SZ_ROW2);          // xrn
  bf16* q_cat    = (bf16*)(arena + 2 * SZ_ROW2);      // [q | ql_flat], reused for proj
  bf16* attn_cat = (bf16*)(arena + 3 * SZ_ROW2);      // [gattn | lattn_flat]
  bf16* poolb    = (bf16*)(arena + 4 * SZ_ROW2);
  bf16* kvG      = (bf16*)(arena + 4 * SZ_ROW2 + SZ_POOL);
  const size_t ARENA_A = 4 * SZ_ROW2 + SZ_POOL + SZ_KVG;
  bf16* xn2 = S1;
  bf16* h1  = (bf16*)(arena + SZ_ROW2);               // clobbers S2/q_cat (dead post-combine)
  bf16* h2  = (bf16*)(arena + SZ_ROW2 + SZ_H);
  const size_t ARENA_B = SZ_ROW2 + 2 * SZ_H;

  float* out  = (float*)d_out;
  float* xres = (float*)d_out;
  const size_t NEED = WT_BYTES + (ARENA_A > ARENA_B ? ARENA_A : ARENA_B);
  if (ws_size < NEED) {
    guard_fill_kernel<<<16, 256, 0, stream>>>(out);
    return;
  }

  bf16* xn = S1;  bf16* xrn = S2;  bf16* kvl = S1;  bf16* proj = q_cat;

  // 0) all weights -> bf16 transposed/merged, one kernel
  convert_all_kernel<<<3072, 256, 0, stream>>>(Gq_w, Lq_w, Gkv_w, Lkv_w, Gp_w, Lp_w,
                                               fc1_w, fc2_w, (bf16*)ws);
  // 1) LayerNorm both streams (wave-per-row, fastest measured form)
  ln_dual_kernel<<<dim3(M_ / 4, 2), 256, 0, stream>>>(x, xrev, g1, b1, xn, xrn);
  // 2) 7x7 pool of xrn
  pool_kernel<<<dim3(TG_, B_), 64, 0, stream>>>(xrn, poolb);
  // 3) q_cat = xn @ [Gq|Lq] + [Gq_b|Lq_b]   (merged Gq+Lq, flat rows; BK=64)
  mfma_gemm_kernel<bf16, false><<<dim3(2, M_ / 128), 256, 0, stream>>>(
      xn, QW_t, Gq_b, Lq_b, nullptr, q_cat, M_, 256, 256);
  // 4) kvl_flat = xrn @ Lkv + b  (flat rows; overwrites S1=xn, now dead; BK=64)
  mfma_gemm_kernel<bf16, false><<<dim3(2, M_ / 128), 256, 0, stream>>>(
      xrn, Lkv_t, Lkv_b, nullptr, nullptr, kvl, M_, 256, 256);
  // 5) kvG = pooled @ Gkv + b  (BK=64)
  mfma_gemm_kernel<bf16, false><<<dim3(2, 8), 256, 0, stream>>>(
      poolb, Gkv_t, Gkv_b, nullptr, nullptr, kvG, 1024, 256, 256);
  // 6) global attention -> attn_cat cols 0-127
  gattn_kernel<<<dim3(Nn / 128, GH_, B_), 256, 0, stream>>>(q_cat, kvG, attn_cat);
  // 7) local attention -> attn_cat cols 128-255 (un-windowed on store)
  lattn_kernel<<<dim3(TG_, B_), 256, 0, stream>>>(q_cat, kvl, attn_cat);
  // 8) proj = attn_cat @ blockdiag(Gp,Lp) + [Gp_b|Lp_b]  (BK=64)
  mfma_gemm_kernel<bf16, false><<<dim3(2, M_ / 128), 256, 0, stream>>>(
      attn_cat, PJ_t, Gp_b, Lp_b, nullptr, proj, M_, 256, 256);
  // 9) xres(=d_out) = x + proj; xn2 = LN2(xres)
  combine_ln_kernel<<<M_ / 8, 256, 0, stream>>>(x, proj, g2, b2, xres, xn2);
  // 10-12) MLP in two halves (2 images each); all GEMMs BK=64; dwconv 2-row
  for (int half = 0; half < 2; half++) {
    const size_t r0 = (size_t)half * 2 * Nn;
    mfma_gemm_kernel<bf16, false><<<dim3(8, (2 * Nn) / 128), 256, 0, stream>>>(
        xn2 + r0 * Cc, f1_t, fc1_b, nullptr, nullptr, h1, 2 * Nn, 1024, 256);
    dwconv_gelu_kernel<<<dim3(Ww / TW_, Hh / 2, 2), 256, 0, stream>>>(h1, dw_w, dw_b, h2);
    mfma_gemm_kernel<float, true><<<dim3(2, (2 * Nn) / 128), 256, 0, stream>>>(
        h2, f2_t, fc2_b, nullptr, xres + r0 * Cc, out + r0 * Cc, 2 * Nn, 256, 1024);
  }
}